// Round 1
// baseline (357.582 us; speedup 1.0000x reference)
//
#include <hip/hip_runtime.h>
#include <math.h>

// Problem constants
#define BB   16
#define CCH  512
#define HWN  4608      // H*W = 96*48
#define HW4  1152      // HWN/4
#define NSE  32
#define BN_EPS 1e-5f

// ---------------------------------------------------------------------------
// Pass 1: xp[b,c] = mean over spatial of x[b,c,:]   (one wave per (b,c) row)
// ---------------------------------------------------------------------------
__global__ __launch_bounds__(64) void k_mean(const float* __restrict__ x,
                                             float* __restrict__ xp) {
    int row = blockIdx.x;                    // b*512 + c
    int tid = threadIdx.x;
    const float4* xr = (const float4*)x + (size_t)row * HW4;
    float s = 0.f;
    #pragma unroll
    for (int k = 0; k < 18; ++k) {           // 18*64 = 1152 float4 = 4608 floats
        float4 v = xr[tid + k * 64];
        s += v.x + v.y + v.z + v.w;
    }
    #pragma unroll
    for (int off = 32; off > 0; off >>= 1)
        s += __shfl_down(s, off);
    if (tid == 0) xp[row] = s * (1.0f / (float)HWN);
}

// ---------------------------------------------------------------------------
// Pass 2 (tiny): SE gate per (b,c); emit gate-folded projection weights
// ---------------------------------------------------------------------------
__global__ __launch_bounds__(512) void k_gate(
    const float* __restrict__ xp,
    const float* __restrict__ se_w1, const float* __restrict__ se_b1,
    const float* __restrict__ se_w2, const float* __restrict__ se_b2,
    const float* __restrict__ g_w, const float* __restrict__ theta_w,
    const float* __restrict__ phi_w,
    float* __restrict__ tw, float* __restrict__ pw, float* __restrict__ gw) {
    __shared__ float xs[CCH];
    __shared__ float hs[NSE];
    int b = blockIdx.x, t = threadIdx.x;
    xs[t] = xp[b * CCH + t];
    __syncthreads();
    if (t < NSE) {
        float a = se_b1[t];
        const float* wr = se_w1 + t * CCH;
        for (int c = 0; c < CCH; ++c) a += wr[c] * xs[c];
        hs[t] = a > 0.f ? a : 0.f;           // relu
    }
    __syncthreads();
    float a = se_b2[t];
    const float* wr = se_w2 + t * NSE;
    #pragma unroll
    for (int j = 0; j < NSE; ++j) a += wr[j] * hs[j];
    float gate = 1.f / (1.f + expf(-a));     // sigmoid
    int idx = b * CCH + t;
    tw[idx] = gate * theta_w[t];
    pw[idx] = gate * phi_w[t];
    gw[idx] = gate * g_w[t];
}

// ---------------------------------------------------------------------------
// Pass 3: partial channel contractions. grid (p_blocks=18, c_chunks=4, B=16)
// Each block: 256 consecutive p, 128 channels. Writes per-chunk partials.
// ---------------------------------------------------------------------------
__global__ __launch_bounds__(256) void k_proj(
    const float* __restrict__ x,
    const float* __restrict__ tw, const float* __restrict__ pw,
    const float* __restrict__ gw,
    float* __restrict__ th_part, float* __restrict__ ph_part,
    float* __restrict__ gx_part) {
    __shared__ float tws[128], pws[128], gws[128];
    int t = threadIdx.x;
    int b = blockIdx.z;
    int c0 = blockIdx.y * 128;
    int p = blockIdx.x * 256 + t;
    if (t < 128) {
        int wi = b * CCH + c0 + t;
        tws[t] = tw[wi]; pws[t] = pw[wi]; gws[t] = gw[wi];
    }
    __syncthreads();
    const float* xr = x + (size_t)(b * CCH + c0) * HWN + p;
    float tha = 0.f, pha = 0.f, gxa = 0.f;
    #pragma unroll 8
    for (int c = 0; c < 128; ++c) {
        float v = xr[(size_t)c * HWN];       // coalesced: 256 lanes contiguous
        tha += tws[c] * v;                   // LDS broadcast (conflict-free)
        pha += pws[c] * v;
        gxa += gws[c] * v;
    }
    int oi = (blockIdx.y * BB + b) * HWN + p;
    th_part[oi] = tha;
    ph_part[oi] = pha;
    gx_part[oi] = gxa;
}

// ---------------------------------------------------------------------------
// Pass 4 (tiny): s[b] = sum_p ph*gx / n ; ths[b,p] = (th+theta_b) * s
// ---------------------------------------------------------------------------
__global__ __launch_bounds__(256) void k_scale(
    const float* __restrict__ th_part, const float* __restrict__ ph_part,
    const float* __restrict__ gx_part,
    const float* __restrict__ theta_b, const float* __restrict__ phi_b,
    const float* __restrict__ g_b,
    float* __restrict__ ths) {
    __shared__ float red[256];
    int b = blockIdx.x, t = threadIdx.x;
    float pb = phi_b[0], gb = g_b[0];
    float acc = 0.f;
    for (int p = t; p < HWN; p += 256) {
        float ph = pb, gx = gb;
        #pragma unroll
        for (int k = 0; k < 4; ++k) {
            int oi = (k * BB + b) * HWN + p;
            ph += ph_part[oi];
            gx += gx_part[oi];
        }
        acc += ph * gx;
    }
    red[t] = acc;
    __syncthreads();
    for (int off = 128; off > 0; off >>= 1) {
        if (t < off) red[t] += red[t + off];
        __syncthreads();
    }
    float s = red[0] * (1.0f / (float)HWN);
    float tb = theta_b[0];
    for (int p = t; p < HWN; p += 256) {
        float th = tb;
        #pragma unroll
        for (int k = 0; k < 4; ++k)
            th += th_part[(k * BB + b) * HWN + p];
        ths[b * HWN + p] = th * s;
    }
}

// ---------------------------------------------------------------------------
// Pass 5: out[b,c,p] = x[b,c,p] + ths[b,p]*A[c] + D[c]
// A = W_w*gamma/sqrt(var+eps); D = (W_b-mean)*inv + beta
// ---------------------------------------------------------------------------
__global__ __launch_bounds__(64) void k_out(
    const float* __restrict__ x, const float* __restrict__ ths,
    const float* __restrict__ W_w, const float* __restrict__ W_b,
    const float* __restrict__ bn_gamma, const float* __restrict__ bn_beta,
    const float* __restrict__ bn_mean, const float* __restrict__ bn_var,
    float* __restrict__ out) {
    int c = blockIdx.x, b = blockIdx.y, t = threadIdx.x;
    float inv = bn_gamma[c] * rsqrtf(bn_var[c] + BN_EPS);
    float A = W_w[c] * inv;
    float Dc = (W_b[c] - bn_mean[c]) * inv + bn_beta[c];
    const float4* xr = (const float4*)x + (size_t)(b * CCH + c) * HW4;
    const float4* tr = (const float4*)ths + (size_t)b * HW4;
    float4* orow = (float4*)out + (size_t)(b * CCH + c) * HW4;
    #pragma unroll
    for (int k = 0; k < 18; ++k) {
        int i = t + k * 64;
        float4 xv = xr[i];
        float4 tv = tr[i];
        float4 o;
        o.x = xv.x + tv.x * A + Dc;
        o.y = xv.y + tv.y * A + Dc;
        o.z = xv.z + tv.z * A + Dc;
        o.w = xv.w + tv.w * A + Dc;
        orow[i] = o;
    }
}

// ---------------------------------------------------------------------------
extern "C" void kernel_launch(void* const* d_in, const int* in_sizes, int n_in,
                              void* d_out, int out_size, void* d_ws, size_t ws_size,
                              hipStream_t stream) {
    const float* x       = (const float*)d_in[0];
    const float* se_w1   = (const float*)d_in[1];
    const float* se_b1   = (const float*)d_in[2];
    const float* se_w2   = (const float*)d_in[3];
    const float* se_b2   = (const float*)d_in[4];
    const float* g_w     = (const float*)d_in[5];
    const float* g_b     = (const float*)d_in[6];
    const float* theta_w = (const float*)d_in[7];
    const float* theta_b = (const float*)d_in[8];
    const float* phi_w   = (const float*)d_in[9];
    const float* phi_b   = (const float*)d_in[10];
    const float* W_w     = (const float*)d_in[11];
    const float* W_b     = (const float*)d_in[12];
    const float* bn_g    = (const float*)d_in[13];
    const float* bn_b    = (const float*)d_in[14];
    const float* bn_m    = (const float*)d_in[15];
    const float* bn_v    = (const float*)d_in[16];
    float* out = (float*)d_out;

    // workspace layout (float offsets)
    float* ws      = (float*)d_ws;
    float* xp      = ws;                          // 8192
    float* tw      = ws + 8192;                   // 8192
    float* pw      = ws + 16384;                  // 8192
    float* gw      = ws + 24576;                  // 8192
    float* th_part = ws + 32768;                  // 4*16*4608 = 294912
    float* ph_part = ws + 32768 + 294912;         // 294912
    float* gx_part = ws + 32768 + 2 * 294912;     // 294912
    float* ths     = ws + 32768 + 3 * 294912;     // 73728
    // total: 991232 floats ~= 3.96 MB

    k_mean<<<BB * CCH, 64, 0, stream>>>(x, xp);
    k_gate<<<BB, CCH, 0, stream>>>(xp, se_w1, se_b1, se_w2, se_b2,
                                   g_w, theta_w, phi_w, tw, pw, gw);
    dim3 gc(HWN / 256, 4, BB);
    k_proj<<<gc, 256, 0, stream>>>(x, tw, pw, gw, th_part, ph_part, gx_part);
    k_scale<<<BB, 256, 0, stream>>>(th_part, ph_part, gx_part,
                                    theta_b, phi_b, g_b, ths);
    dim3 gd(CCH, BB);
    k_out<<<gd, 64, 0, stream>>>(x, ths, W_w, W_b, bn_g, bn_b, bn_m, bn_v, out);
}